// Round 1
// baseline (209.116 us; speedup 1.0000x reference)
//
#include <hip/hip_runtime.h>

typedef short bf16x8 __attribute__((ext_vector_type(8)));
typedef float f32x4 __attribute__((ext_vector_type(4)));

__device__ __forceinline__ unsigned short f2bf(float f) {
  union { float f; unsigned int u; } v; v.f = f;
  unsigned int r = v.u + 0x7FFFu + ((v.u >> 16) & 1u);
  return (unsigned short)(r >> 16);
}

__device__ __forceinline__ void gld_lds16(const void* g, void* l) {
  __builtin_amdgcn_global_load_lds(
      (const __attribute__((address_space(1))) unsigned int*)g,
      (__attribute__((address_space(3))) unsigned int*)l, 16, 0, 0);
}

// ---------------- prep kernels ----------------

__global__ __launch_bounds__(256) void k_convert_x(const float4* __restrict__ in,
                                                   ushort4* __restrict__ out) {
  int id = blockIdx.x * 256 + threadIdx.x;   // exactly 4M/4 threads
  float4 v = in[id];
  ushort4 o;
  o.x = f2bf(v.x); o.y = f2bf(v.y); o.z = f2bf(v.z); o.w = f2bf(v.w);
  out[id] = o;
}

// in [R][C] fp32 -> out [C][R] bf16
__global__ __launch_bounds__(256) void k_transpose_bf16(const float* __restrict__ in,
                                                        unsigned short* __restrict__ out,
                                                        int R, int C) {
  __shared__ float tile[32][33];
  int tx = threadIdx.x, ty = threadIdx.y;
  int c0 = blockIdx.x * 32, r0 = blockIdx.y * 32;
#pragma unroll
  for (int i = 0; i < 32; i += 8) tile[ty + i][tx] = in[(size_t)(r0 + ty + i) * C + c0 + tx];
  __syncthreads();
#pragma unroll
  for (int i = 0; i < 32; i += 8) out[(size_t)(c0 + ty + i) * R + r0 + tx] = f2bf(tile[tx][ty + i]);
}

// bias_table [4095][16] -> biash [16][4096]
__global__ __launch_bounds__(256) void k_bias_cols(const float* __restrict__ bt,
                                                   float* __restrict__ bh) {
  int i = blockIdx.x * 256 + threadIdx.x;
  if (i < 4095 * 16) bh[(i & 15) * 4096 + (i >> 4)] = bt[i];
}

// ---------------- GEMM: C[M][N] = A[M][1024] * Bt[N][1024]^T (+bias) ----------------
// EPI==0: write fp32 Cf[m*1024+n]   (proj)
// EPI==1: scatter q(*0.125)/k -> [B,H,L,64] bf16, v -> transposed [B,H,64,L] bf16 (qkv)
template <int EPI>
__global__ __launch_bounds__(256) void k_gemm(const unsigned short* __restrict__ A,
                                              const unsigned short* __restrict__ Bt,
                                              const float* __restrict__ bias,
                                              float* __restrict__ Cf,
                                              unsigned short* __restrict__ qb,
                                              unsigned short* __restrict__ kb,
                                              unsigned short* __restrict__ vtb) {
  __shared__ unsigned short Alds[128 * 64];
  __shared__ unsigned short Blds[128 * 64];
  const int t = threadIdx.x;
  const int l = t & 63, w = t >> 6;
  const int l15 = l & 15, l4 = l >> 4;
  const int wm = w >> 1, wn = w & 1;
  const int bm = blockIdx.y * 128, bn = blockIdx.x * 128;

  const int srow = t >> 3;                   // 0..31
  const int scl = (t & 7) ^ (srow & 7);      // pre-swizzled logical chunk
  const unsigned short* ag = A + (size_t)(bm + srow) * 1024 + scl * 8;
  const unsigned short* bg = Bt + (size_t)(bn + srow) * 1024 + scl * 8;

  f32x4 acc[4][4];
#pragma unroll
  for (int i = 0; i < 4; ++i)
#pragma unroll
    for (int j = 0; j < 4; ++j) acc[i][j] = (f32x4){0.f, 0.f, 0.f, 0.f};

  for (int kt = 0; kt < 16; ++kt) {
#pragma unroll
    for (int q = 0; q < 4; ++q) {
      gld_lds16(ag + (size_t)q * 32 * 1024 + kt * 64, &Alds[(q * 256 + t) * 8]);
      gld_lds16(bg + (size_t)q * 32 * 1024 + kt * 64, &Blds[(q * 256 + t) * 8]);
    }
    __syncthreads();
#pragma unroll
    for (int kc = 0; kc < 2; ++kc) {
      bf16x8 af[4], bv[4];
#pragma unroll
      for (int i = 0; i < 4; ++i) {
        int ra = wm * 64 + i * 16 + l15;
        af[i] = *(const bf16x8*)&Alds[ra * 64 + (((kc * 4 + l4) ^ (l15 & 7))) * 8];
        int rb = wn * 64 + i * 16 + l15;
        bv[i] = *(const bf16x8*)&Blds[rb * 64 + (((kc * 4 + l4) ^ (l15 & 7))) * 8];
      }
#pragma unroll
      for (int i = 0; i < 4; ++i)
#pragma unroll
        for (int jn = 0; jn < 4; ++jn)
          acc[i][jn] = __builtin_amdgcn_mfma_f32_16x16x32_bf16(af[i], bv[jn], acc[i][jn], 0, 0, 0);
    }
    __syncthreads();
  }

#pragma unroll
  for (int i = 0; i < 4; ++i) {
#pragma unroll
    for (int jn = 0; jn < 4; ++jn) {
      int n = bn + wn * 64 + jn * 16 + l15;
      float bval = bias[n];
#pragma unroll
      for (int j = 0; j < 4; ++j) {
        int m = bm + wm * 64 + i * 16 + l4 * 4 + j;
        float v = acc[i][jn][j] + bval;
        if (EPI == 0) {
          Cf[(size_t)m * 1024 + n] = v;
        } else {
          int which = n >> 10, hh = (n >> 6) & 15, d = n & 63;
          int bb = m >> 11, pos = m & 2047;
          int bhh = bb * 16 + hh;
          if (which == 0)
            qb[((size_t)bhh * 2048 + pos) * 64 + d] = f2bf(v * 0.125f);
          else if (which == 1)
            kb[((size_t)bhh * 2048 + pos) * 64 + d] = f2bf(v);
          else
            vtb[((size_t)bhh * 64 + d) * 2048 + pos] = f2bf(v);
        }
      }
    }
  }
}

// ---------------- flash attention with rel-pos bias ----------------
// grid: (16 qtiles, 32 bh); 512 threads = 8 waves, wave handles 16 query rows
__global__ __launch_bounds__(512) void k_attn(const unsigned short* __restrict__ qbuf,
                                              const unsigned short* __restrict__ kbuf,
                                              const unsigned short* __restrict__ vtbuf,
                                              const float* __restrict__ biash,
                                              unsigned short* __restrict__ aout) {
  __shared__ unsigned short Klds[64 * 64];
  __shared__ unsigned short Vlds[64 * 64];
  __shared__ unsigned short Plds[8 * 16 * 72];
  __shared__ float blds[192];

  const int t = threadIdx.x;
  const int w = t >> 6, l = t & 63;
  const int l15 = l & 15, l4 = l >> 4;
  const int bh = blockIdx.y;
  const int h = bh & 15, b = bh >> 4;
  const int qbase = blockIdx.x * 128;

  const int qrow = qbase + w * 16 + l15;
  const size_t qoff = ((size_t)bh * 2048 + qrow) * 64;
  bf16x8 qf0 = *(const bf16x8*)&qbuf[qoff + l4 * 8];
  bf16x8 qf1 = *(const bf16x8*)&qbuf[qoff + 32 + l4 * 8];

  f32x4 O[4];
#pragma unroll
  for (int i = 0; i < 4; ++i) O[i] = (f32x4){0.f, 0.f, 0.f, 0.f};
  float m_run[4], l_run[4];
#pragma unroll
  for (int j = 0; j < 4; ++j) { m_run[j] = -1e30f; l_run[j] = 0.f; }

  const int srow = t >> 3;                 // 0..63
  const int scl = (t & 7) ^ (srow & 7);
  const unsigned short* kg = kbuf + ((size_t)bh * 2048 + srow) * 64 + scl * 8;
  const unsigned short* vg = vtbuf + ((size_t)bh * 64 + srow) * 2048 + scl * 8;
  unsigned short* kl = &Klds[t * 8];
  unsigned short* vl = &Vlds[t * 8];
  const float* bcol = biash + h * 4096;
  const int boff = 1920 - qbase;

  unsigned short* pw = &Plds[w * 1152];
  const int qloc = l4 * 4;

  for (int kbase = 0; kbase < 2048; kbase += 64) {
    gld_lds16(kg + (size_t)kbase * 64, kl);
    gld_lds16(vg + kbase, vl);
    if (t < 191) blds[t] = bcol[boff + kbase + t];
    __syncthreads();

    // S = (q*scale) . k + bias
    float s[4][4];
#pragma unroll
    for (int f = 0; f < 4; ++f) {
      int kr = f * 16 + l15;
      int sw = l15 & 7;
      bf16x8 k0 = *(const bf16x8*)&Klds[kr * 64 + ((l4 ^ sw)) * 8];
      bf16x8 k1 = *(const bf16x8*)&Klds[kr * 64 + (((4 + l4) ^ sw)) * 8];
      f32x4 facc = (f32x4){0.f, 0.f, 0.f, 0.f};
      facc = __builtin_amdgcn_mfma_f32_16x16x32_bf16(qf0, k0, facc, 0, 0, 0);
      facc = __builtin_amdgcn_mfma_f32_16x16x32_bf16(qf1, k1, facc, 0, 0, 0);
#pragma unroll
      for (int j = 0; j < 4; ++j)
        s[f][j] = facc[j] + blds[f * 16 + l15 - (w * 16 + qloc + j) + 127];
    }

    // online softmax, row = w*16 + l4*4 + j (64 keys live in the 16 lanes sharing l4)
#pragma unroll
    for (int j = 0; j < 4; ++j) {
      float mx = fmaxf(fmaxf(s[0][j], s[1][j]), fmaxf(s[2][j], s[3][j]));
#pragma unroll
      for (int off = 1; off < 16; off <<= 1) mx = fmaxf(mx, __shfl_xor(mx, off));
      float mnew = fmaxf(m_run[j], mx);
      float alpha = __expf(m_run[j] - mnew);
      m_run[j] = mnew;
      float rs = 0.f;
#pragma unroll
      for (int f = 0; f < 4; ++f) {
        float p = __expf(s[f][j] - mnew);
        s[f][j] = p;
        rs += p;
      }
#pragma unroll
      for (int off = 1; off < 16; off <<= 1) rs += __shfl_xor(rs, off);
      l_run[j] = l_run[j] * alpha + rs;
#pragma unroll
      for (int df = 0; df < 4; ++df) O[df][j] *= alpha;
    }

    // P -> per-wave LDS (transpose C-layout -> A-layout)
#pragma unroll
    for (int f = 0; f < 4; ++f)
#pragma unroll
      for (int j = 0; j < 4; ++j)
        pw[(qloc + j) * 72 + f * 16 + l15] = f2bf(s[f][j]);

    // O += P * V
    bf16x8 pa0 = *(const bf16x8*)&pw[l15 * 72 + l4 * 8];
    bf16x8 pa1 = *(const bf16x8*)&pw[l15 * 72 + 32 + l4 * 8];
#pragma unroll
    for (int df = 0; df < 4; ++df) {
      int vr = df * 16 + l15;
      int sw = l15 & 7;
      bf16x8 v0 = *(const bf16x8*)&Vlds[vr * 64 + ((l4 ^ sw)) * 8];
      bf16x8 v1 = *(const bf16x8*)&Vlds[vr * 64 + (((4 + l4) ^ sw)) * 8];
      O[df] = __builtin_amdgcn_mfma_f32_16x16x32_bf16(pa0, v0, O[df], 0, 0, 0);
      O[df] = __builtin_amdgcn_mfma_f32_16x16x32_bf16(pa1, v1, O[df], 0, 0, 0);
    }
    __syncthreads();
  }

#pragma unroll
  for (int df = 0; df < 4; ++df)
#pragma unroll
    for (int j = 0; j < 4; ++j) {
      float v = O[df][j] / l_run[j];
      int q = qbase + w * 16 + qloc + j;
      int col = h * 64 + df * 16 + l15;
      aout[((size_t)b * 2048 + q) * 1024 + col] = f2bf(v);
    }
}

// ---------------- launch ----------------

extern "C" void kernel_launch(void* const* d_in, const int* in_sizes, int n_in,
                              void* d_out, int out_size, void* d_ws, size_t ws_size,
                              hipStream_t stream) {
  const float* x = (const float*)d_in[0];
  const float* qkv_w = (const float*)d_in[1];
  const float* qkv_b = (const float*)d_in[2];
  const float* proj_w = (const float*)d_in[3];
  const float* proj_b = (const float*)d_in[4];
  const float* bias_table = (const float*)d_in[5];
  float* out = (float*)d_out;

  char* ws = (char*)d_ws;
  unsigned short* xb = (unsigned short*)(ws);                        // 8 MB, reused as attn_out
  unsigned short* wqkv = (unsigned short*)(ws + (size_t)(8u << 20));   // 6 MB
  unsigned short* wproj = (unsigned short*)(ws + (size_t)(14u << 20)); // 2 MB
  unsigned short* qb = (unsigned short*)(ws + (size_t)(16u << 20));    // 8 MB
  unsigned short* kb = (unsigned short*)(ws + (size_t)(24u << 20));    // 8 MB
  unsigned short* vtb = (unsigned short*)(ws + (size_t)(32u << 20));   // 8 MB
  float* biash = (float*)(ws + (size_t)(40u << 20));                   // 256 KB

  unsigned short* attn_out = xb;  // xb is dead after the qkv GEMM

  k_convert_x<<<dim3(4096), dim3(256), 0, stream>>>((const float4*)x, (ushort4*)xb);
  k_transpose_bf16<<<dim3(96, 32), dim3(32, 8), 0, stream>>>(qkv_w, wqkv, 1024, 3072);
  k_transpose_bf16<<<dim3(32, 32), dim3(32, 8), 0, stream>>>(proj_w, wproj, 1024, 1024);
  k_bias_cols<<<dim3(256), dim3(256), 0, stream>>>(bias_table, biash);

  k_gemm<1><<<dim3(24, 32), dim3(256), 0, stream>>>(xb, wqkv, qkv_b, nullptr, qb, kb, vtb);
  k_attn<<<dim3(16, 32), dim3(512), 0, stream>>>(qb, kb, vtb, biash, attn_out);
  k_gemm<0><<<dim3(8, 32), dim3(256), 0, stream>>>(attn_out, wproj, proj_b, out, nullptr, nullptr,
                                                   nullptr);
}

// Round 2
// 204.360 us; speedup vs baseline: 1.0233x; 1.0233x over previous
//
#include <hip/hip_runtime.h>

typedef short bf16x8 __attribute__((ext_vector_type(8)));
typedef float f32x4 __attribute__((ext_vector_type(4)));

__device__ __forceinline__ unsigned short f2bf(float f) {
  union { float f; unsigned int u; } v; v.f = f;
  unsigned int r = v.u + 0x7FFFu + ((v.u >> 16) & 1u);
  return (unsigned short)(r >> 16);
}

__device__ __forceinline__ float exp2_fast(float x) {
  float r;
  asm("v_exp_f32 %0, %1" : "=v"(r) : "v"(x));
  return r;
}

__device__ __forceinline__ void gld_lds16(const void* g, void* l) {
  __builtin_amdgcn_global_load_lds(
      (const __attribute__((address_space(1))) unsigned int*)g,
      (__attribute__((address_space(3))) unsigned int*)l, 16, 0, 0);
}

__device__ __forceinline__ void gld_lds4(const void* g, void* l) {
  __builtin_amdgcn_global_load_lds(
      (const __attribute__((address_space(1))) unsigned int*)g,
      (__attribute__((address_space(3))) unsigned int*)l, 4, 0, 0);
}

// ---------------- prep kernels ----------------

__global__ __launch_bounds__(256) void k_convert_x(const float4* __restrict__ in,
                                                   ushort4* __restrict__ out) {
  int id = blockIdx.x * 256 + threadIdx.x;   // exactly 4M/4 threads
  float4 v = in[id];
  ushort4 o;
  o.x = f2bf(v.x); o.y = f2bf(v.y); o.z = f2bf(v.z); o.w = f2bf(v.w);
  out[id] = o;
}

// in [R][C] fp32 -> out [C][R] bf16
__global__ __launch_bounds__(256) void k_transpose_bf16(const float* __restrict__ in,
                                                        unsigned short* __restrict__ out,
                                                        int R, int C) {
  __shared__ float tile[32][33];
  int tx = threadIdx.x, ty = threadIdx.y;
  int c0 = blockIdx.x * 32, r0 = blockIdx.y * 32;
#pragma unroll
  for (int i = 0; i < 32; i += 8) tile[ty + i][tx] = in[(size_t)(r0 + ty + i) * C + c0 + tx];
  __syncthreads();
#pragma unroll
  for (int i = 0; i < 32; i += 8) out[(size_t)(c0 + ty + i) * R + r0 + tx] = f2bf(tile[tx][ty + i]);
}

// bias_table [4095][16] -> biash [16][4096], scaled by log2(e) for exp2-domain softmax
__global__ __launch_bounds__(256) void k_bias_cols(const float* __restrict__ bt,
                                                   float* __restrict__ bh) {
  int i = blockIdx.x * 256 + threadIdx.x;
  if (i < 4095 * 16) bh[(i & 15) * 4096 + (i >> 4)] = bt[i] * 1.44269504089f;
}

// ---------------- GEMM: C[M][N] = A[M][1024] * Bt[N][1024]^T (+bias) ----------------
// EPI==0: write fp32 Cf[m*1024+n]   (proj)
// EPI==1: scatter q(*0.125*log2e)/k -> [B,H,L,64] bf16, v -> transposed [B,H,64,L] bf16 (qkv)
template <int EPI>
__global__ __launch_bounds__(256) void k_gemm(const unsigned short* __restrict__ A,
                                              const unsigned short* __restrict__ Bt,
                                              const float* __restrict__ bias,
                                              float* __restrict__ Cf,
                                              unsigned short* __restrict__ qb,
                                              unsigned short* __restrict__ kb,
                                              unsigned short* __restrict__ vtb) {
  __shared__ unsigned short Alds[128 * 64];
  __shared__ unsigned short Blds[128 * 64];
  const int t = threadIdx.x;
  const int l = t & 63, w = t >> 6;
  const int l15 = l & 15, l4 = l >> 4;
  const int wm = w >> 1, wn = w & 1;
  const int bm = blockIdx.y * 128, bn = blockIdx.x * 128;

  const int srow = t >> 3;                   // 0..31
  const int scl = (t & 7) ^ (srow & 7);      // pre-swizzled logical chunk
  const unsigned short* ag = A + (size_t)(bm + srow) * 1024 + scl * 8;
  const unsigned short* bg = Bt + (size_t)(bn + srow) * 1024 + scl * 8;

  f32x4 acc[4][4];
#pragma unroll
  for (int i = 0; i < 4; ++i)
#pragma unroll
    for (int j = 0; j < 4; ++j) acc[i][j] = (f32x4){0.f, 0.f, 0.f, 0.f};

  for (int kt = 0; kt < 16; ++kt) {
#pragma unroll
    for (int q = 0; q < 4; ++q) {
      gld_lds16(ag + (size_t)q * 32 * 1024 + kt * 64, &Alds[(q * 256 + t) * 8]);
      gld_lds16(bg + (size_t)q * 32 * 1024 + kt * 64, &Blds[(q * 256 + t) * 8]);
    }
    __syncthreads();
#pragma unroll
    for (int kc = 0; kc < 2; ++kc) {
      bf16x8 af[4], bv[4];
#pragma unroll
      for (int i = 0; i < 4; ++i) {
        int ra = wm * 64 + i * 16 + l15;
        af[i] = *(const bf16x8*)&Alds[ra * 64 + (((kc * 4 + l4) ^ (l15 & 7))) * 8];
        int rb = wn * 64 + i * 16 + l15;
        bv[i] = *(const bf16x8*)&Blds[rb * 64 + (((kc * 4 + l4) ^ (l15 & 7))) * 8];
      }
#pragma unroll
      for (int i = 0; i < 4; ++i)
#pragma unroll
        for (int jn = 0; jn < 4; ++jn)
          acc[i][jn] = __builtin_amdgcn_mfma_f32_16x16x32_bf16(af[i], bv[jn], acc[i][jn], 0, 0, 0);
    }
    __syncthreads();
  }

#pragma unroll
  for (int i = 0; i < 4; ++i) {
#pragma unroll
    for (int jn = 0; jn < 4; ++jn) {
      int n = bn + wn * 64 + jn * 16 + l15;
      float bval = bias[n];
#pragma unroll
      for (int j = 0; j < 4; ++j) {
        int m = bm + wm * 64 + i * 16 + l4 * 4 + j;
        float v = acc[i][jn][j] + bval;
        if (EPI == 0) {
          Cf[(size_t)m * 1024 + n] = v;
        } else {
          int which = n >> 10, hh = (n >> 6) & 15, d = n & 63;
          int bb = m >> 11, pos = m & 2047;
          int bhh = bb * 16 + hh;
          if (which == 0)
            qb[((size_t)bhh * 2048 + pos) * 64 + d] = f2bf(v * 0.18033688f);  // 0.125*log2(e)
          else if (which == 1)
            kb[((size_t)bhh * 2048 + pos) * 64 + d] = f2bf(v);
          else
            vtb[((size_t)bhh * 64 + d) * 2048 + pos] = f2bf(v);
        }
      }
    }
  }
}

// ---------------- flash attention with rel-pos bias ----------------
// grid: (16 qtiles, 32 bh); 512 threads = 8 waves, wave handles 16 query rows
// double-buffered K/V, bias window prestaged, exp2-domain online softmax
__global__ __launch_bounds__(512) void k_attn(const unsigned short* __restrict__ qbuf,
                                              const unsigned short* __restrict__ kbuf,
                                              const unsigned short* __restrict__ vtbuf,
                                              const float* __restrict__ biash,
                                              unsigned short* __restrict__ aout) {
  __shared__ unsigned short Klds[2][64 * 64];
  __shared__ unsigned short Vlds[2][64 * 64];
  __shared__ unsigned short Plds[8 * 16 * 72];
  __shared__ float blds[2176];

  const int t = threadIdx.x;
  const int w = t >> 6, l = t & 63;
  const int l15 = l & 15, l4 = l >> 4;
  const int bh = blockIdx.y;
  const int h = bh & 15, b = bh >> 4;
  const int qbase = blockIdx.x * 128;

  const int qrow = qbase + w * 16 + l15;
  const size_t qoff = ((size_t)bh * 2048 + qrow) * 64;
  bf16x8 qf0 = *(const bf16x8*)&qbuf[qoff + l4 * 8];
  bf16x8 qf1 = *(const bf16x8*)&qbuf[qoff + 32 + l4 * 8];

  f32x4 O[4];
#pragma unroll
  for (int i = 0; i < 4; ++i) O[i] = (f32x4){0.f, 0.f, 0.f, 0.f};
  float m_run[4], l_run[4];
#pragma unroll
  for (int j = 0; j < 4; ++j) { m_run[j] = -1e30f; l_run[j] = 0.f; }

  const int srow = t >> 3;                 // 0..63
  const int scl = (t & 7) ^ (srow & 7);
  const unsigned short* kg = kbuf + ((size_t)bh * 2048 + srow) * 64 + scl * 8;
  const unsigned short* vg = vtbuf + ((size_t)bh * 64 + srow) * 2048 + scl * 8;

  // prologue: stage tile 0 + entire bias window (k-q+2047 in [1920-qbase, 4094-qbase])
  gld_lds16(kg, &Klds[0][t * 8]);
  gld_lds16(vg, &Vlds[0][t * 8]);
  {
    const float* bwin = biash + h * 4096 + (1920 - qbase);
#pragma unroll
    for (int i = 0; i < 5; ++i) {
      int idx = t + i * 512;
      if (idx < 2176) gld_lds4(bwin + idx, &blds[idx]);
    }
  }
  __syncthreads();

  unsigned short* pw = &Plds[w * 1152];
  const int qloc = l4 * 4;
  const int brel = l15 - w * 16 - qloc + 127;  // + kbase + f*16 - j at use

  for (int kt = 0; kt < 32; ++kt) {
    const int cur = kt & 1;
    if (kt < 31) {  // prefetch next tile into other buffer (hidden under compute)
      gld_lds16(kg + (size_t)(kt + 1) * 64 * 64, &Klds[cur ^ 1][t * 8]);
      gld_lds16(vg + (kt + 1) * 64, &Vlds[cur ^ 1][t * 8]);
    }
    const int kbase = kt * 64;

    // S = (q*scale*log2e) . k + bias*log2e
    float s[4][4];
    __builtin_amdgcn_s_setprio(1);
#pragma unroll
    for (int f = 0; f < 4; ++f) {
      int kr = f * 16 + l15;
      int sw = l15 & 7;
      bf16x8 k0 = *(const bf16x8*)&Klds[cur][kr * 64 + ((l4 ^ sw)) * 8];
      bf16x8 k1 = *(const bf16x8*)&Klds[cur][kr * 64 + (((4 + l4) ^ sw)) * 8];
      f32x4 facc = (f32x4){0.f, 0.f, 0.f, 0.f};
      facc = __builtin_amdgcn_mfma_f32_16x16x32_bf16(qf0, k0, facc, 0, 0, 0);
      facc = __builtin_amdgcn_mfma_f32_16x16x32_bf16(qf1, k1, facc, 0, 0, 0);
#pragma unroll
      for (int j = 0; j < 4; ++j)
        s[f][j] = facc[j] + blds[kbase + f * 16 + brel - j];
    }
    __builtin_amdgcn_s_setprio(0);

    // online softmax (exp2 domain), row = w*16 + l4*4 + j
#pragma unroll
    for (int j = 0; j < 4; ++j) {
      float mx = fmaxf(fmaxf(s[0][j], s[1][j]), fmaxf(s[2][j], s[3][j]));
#pragma unroll
      for (int off = 1; off < 16; off <<= 1) mx = fmaxf(mx, __shfl_xor(mx, off));
      float mnew = fmaxf(m_run[j], mx);
      float alpha = exp2_fast(m_run[j] - mnew);
      m_run[j] = mnew;
      float rs = 0.f;
#pragma unroll
      for (int f = 0; f < 4; ++f) {
        float p = exp2_fast(s[f][j] - mnew);
        s[f][j] = p;
        rs += p;
      }
#pragma unroll
      for (int off = 1; off < 16; off <<= 1) rs += __shfl_xor(rs, off);
      l_run[j] = l_run[j] * alpha + rs;
#pragma unroll
      for (int df = 0; df < 4; ++df) O[df][j] *= alpha;
    }

    // P -> per-wave LDS (transpose C-layout -> A-layout)
#pragma unroll
    for (int f = 0; f < 4; ++f)
#pragma unroll
      for (int j = 0; j < 4; ++j)
        pw[(qloc + j) * 72 + f * 16 + l15] = f2bf(s[f][j]);

    // O += P * V
    bf16x8 pa0 = *(const bf16x8*)&pw[l15 * 72 + l4 * 8];
    bf16x8 pa1 = *(const bf16x8*)&pw[l15 * 72 + 32 + l4 * 8];
    __builtin_amdgcn_s_setprio(1);
#pragma unroll
    for (int df = 0; df < 4; ++df) {
      int vr = df * 16 + l15;
      int sw = l15 & 7;
      bf16x8 v0 = *(const bf16x8*)&Vlds[cur][vr * 64 + ((l4 ^ sw)) * 8];
      bf16x8 v1 = *(const bf16x8*)&Vlds[cur][vr * 64 + (((4 + l4) ^ sw)) * 8];
      O[df] = __builtin_amdgcn_mfma_f32_16x16x32_bf16(pa0, v0, O[df], 0, 0, 0);
      O[df] = __builtin_amdgcn_mfma_f32_16x16x32_bf16(pa1, v1, O[df], 0, 0, 0);
    }
    __builtin_amdgcn_s_setprio(0);

    __syncthreads();  // drains prefetch vmcnt; publishes next buffer; protects cur^1 overwrite
  }

#pragma unroll
  for (int df = 0; df < 4; ++df)
#pragma unroll
    for (int j = 0; j < 4; ++j) {
      float v = O[df][j] / l_run[j];
      int q = qbase + w * 16 + qloc + j;
      int col = h * 64 + df * 16 + l15;
      aout[((size_t)b * 2048 + q) * 1024 + col] = f2bf(v);
    }
}

// ---------------- launch ----------------

extern "C" void kernel_launch(void* const* d_in, const int* in_sizes, int n_in,
                              void* d_out, int out_size, void* d_ws, size_t ws_size,
                              hipStream_t stream) {
  const float* x = (const float*)d_in[0];
  const float* qkv_w = (const float*)d_in[1];
  const float* qkv_b = (const float*)d_in[2];
  const float* proj_w = (const float*)d_in[3];
  const float* proj_b = (const float*)d_in[4];
  const float* bias_table = (const float*)d_in[5];
  float* out = (float*)d_out;

  char* ws = (char*)d_ws;
  unsigned short* xb = (unsigned short*)(ws);                        // 8 MB, reused as attn_out
  unsigned short* wqkv = (unsigned short*)(ws + (size_t)(8u << 20));   // 6 MB
  unsigned short* wproj = (unsigned short*)(ws + (size_t)(14u << 20)); // 2 MB
  unsigned short* qb = (unsigned short*)(ws + (size_t)(16u << 20));    // 8 MB
  unsigned short* kb = (unsigned short*)(ws + (size_t)(24u << 20));    // 8 MB
  unsigned short* vtb = (unsigned short*)(ws + (size_t)(32u << 20));   // 8 MB
  float* biash = (float*)(ws + (size_t)(40u << 20));                   // 256 KB

  unsigned short* attn_out = xb;  // xb is dead after the qkv GEMM

  k_convert_x<<<dim3(4096), dim3(256), 0, stream>>>((const float4*)x, (ushort4*)xb);
  k_transpose_bf16<<<dim3(96, 32), dim3(32, 8), 0, stream>>>(qkv_w, wqkv, 1024, 3072);
  k_transpose_bf16<<<dim3(32, 32), dim3(32, 8), 0, stream>>>(proj_w, wproj, 1024, 1024);
  k_bias_cols<<<dim3(256), dim3(256), 0, stream>>>(bias_table, biash);

  k_gemm<1><<<dim3(24, 32), dim3(256), 0, stream>>>(xb, wqkv, qkv_b, nullptr, qb, kb, vtb);
  k_attn<<<dim3(16, 32), dim3(512), 0, stream>>>(qb, kb, vtb, biash, attn_out);
  k_gemm<0><<<dim3(8, 32), dim3(256), 0, stream>>>(attn_out, wproj, proj_b, out, nullptr, nullptr,
                                                   nullptr);
}

// Round 3
// 172.003 us; speedup vs baseline: 1.2158x; 1.1881x over previous
//
#include <hip/hip_runtime.h>

typedef short bf16x8 __attribute__((ext_vector_type(8)));
typedef float f32x4 __attribute__((ext_vector_type(4)));
typedef unsigned int u32x2 __attribute__((ext_vector_type(2)));

__device__ __forceinline__ unsigned short f2bf(float f) {
  union { float f; unsigned int u; } v; v.f = f;
  unsigned int r = v.u + 0x7FFFu + ((v.u >> 16) & 1u);
  return (unsigned short)(r >> 16);
}

__device__ __forceinline__ float exp2_fast(float x) {
  float r;
  asm("v_exp_f32 %0, %1" : "=v"(r) : "v"(x));
  return r;
}

__device__ __forceinline__ unsigned int cvt_pk_bf16(float lo, float hi) {
  unsigned int r;
  asm("v_cvt_pk_bf16_f32 %0, %1, %2" : "=v"(r) : "v"(lo), "v"(hi));
  return r;
}

__device__ __forceinline__ void gld_lds16(const void* g, void* l) {
  __builtin_amdgcn_global_load_lds(
      (const __attribute__((address_space(1))) unsigned int*)g,
      (__attribute__((address_space(3))) unsigned int*)l, 16, 0, 0);
}

// ---------------- prep kernels ----------------

__global__ __launch_bounds__(256) void k_convert_x(const float4* __restrict__ in,
                                                   ushort4* __restrict__ out) {
  int id = blockIdx.x * 256 + threadIdx.x;   // exactly 4M/4 threads
  float4 v = in[id];
  ushort4 o;
  o.x = f2bf(v.x); o.y = f2bf(v.y); o.z = f2bf(v.z); o.w = f2bf(v.w);
  out[id] = o;
}

// in [R][C] fp32 -> out [C][R] bf16
__global__ __launch_bounds__(256) void k_transpose_bf16(const float* __restrict__ in,
                                                        unsigned short* __restrict__ out,
                                                        int R, int C) {
  __shared__ float tile[32][33];
  int tx = threadIdx.x, ty = threadIdx.y;
  int c0 = blockIdx.x * 32, r0 = blockIdx.y * 32;
#pragma unroll
  for (int i = 0; i < 32; i += 8) tile[ty + i][tx] = in[(size_t)(r0 + ty + i) * C + c0 + tx];
  __syncthreads();
#pragma unroll
  for (int i = 0; i < 32; i += 8) out[(size_t)(c0 + ty + i) * R + r0 + tx] = f2bf(tile[tx][ty + i]);
}

// bias_table [4095][16] -> biash [16][4096], scaled by log2(e) for exp2-domain softmax
__global__ __launch_bounds__(256) void k_bias_cols(const float* __restrict__ bt,
                                                   float* __restrict__ bh) {
  int i = blockIdx.x * 256 + threadIdx.x;
  if (i < 4095 * 16) bh[(i & 15) * 4096 + (i >> 4)] = bt[i] * 1.44269504089f;
}

// ---------------- GEMM: C[M][N] = A[M][1024] * Bt[N][1024]^T (+bias) ----------------
template <int EPI>
__global__ __launch_bounds__(256) void k_gemm(const unsigned short* __restrict__ A,
                                              const unsigned short* __restrict__ Bt,
                                              const float* __restrict__ bias,
                                              float* __restrict__ Cf,
                                              unsigned short* __restrict__ qb,
                                              unsigned short* __restrict__ kb,
                                              unsigned short* __restrict__ vtb) {
  __shared__ unsigned short Alds[128 * 64];
  __shared__ unsigned short Blds[128 * 64];
  const int t = threadIdx.x;
  const int l = t & 63, w = t >> 6;
  const int l15 = l & 15, l4 = l >> 4;
  const int wm = w >> 1, wn = w & 1;
  const int bm = blockIdx.y * 128, bn = blockIdx.x * 128;

  const int srow = t >> 3;
  const int scl = (t & 7) ^ (srow & 7);
  const unsigned short* ag = A + (size_t)(bm + srow) * 1024 + scl * 8;
  const unsigned short* bg = Bt + (size_t)(bn + srow) * 1024 + scl * 8;

  f32x4 acc[4][4];
#pragma unroll
  for (int i = 0; i < 4; ++i)
#pragma unroll
    for (int j = 0; j < 4; ++j) acc[i][j] = (f32x4){0.f, 0.f, 0.f, 0.f};

  for (int kt = 0; kt < 16; ++kt) {
#pragma unroll
    for (int q = 0; q < 4; ++q) {
      gld_lds16(ag + (size_t)q * 32 * 1024 + kt * 64, &Alds[(q * 256 + t) * 8]);
      gld_lds16(bg + (size_t)q * 32 * 1024 + kt * 64, &Blds[(q * 256 + t) * 8]);
    }
    __syncthreads();
#pragma unroll
    for (int kc = 0; kc < 2; ++kc) {
      bf16x8 af[4], bv[4];
#pragma unroll
      for (int i = 0; i < 4; ++i) {
        int ra = wm * 64 + i * 16 + l15;
        af[i] = *(const bf16x8*)&Alds[ra * 64 + (((kc * 4 + l4) ^ (l15 & 7))) * 8];
        int rb = wn * 64 + i * 16 + l15;
        bv[i] = *(const bf16x8*)&Blds[rb * 64 + (((kc * 4 + l4) ^ (l15 & 7))) * 8];
      }
#pragma unroll
      for (int i = 0; i < 4; ++i)
#pragma unroll
        for (int jn = 0; jn < 4; ++jn)
          acc[i][jn] = __builtin_amdgcn_mfma_f32_16x16x32_bf16(af[i], bv[jn], acc[i][jn], 0, 0, 0);
    }
    __syncthreads();
  }

#pragma unroll
  for (int i = 0; i < 4; ++i) {
#pragma unroll
    for (int jn = 0; jn < 4; ++jn) {
      int n = bn + wn * 64 + jn * 16 + l15;
      float bval = bias[n];
#pragma unroll
      for (int j = 0; j < 4; ++j) {
        int m = bm + wm * 64 + i * 16 + l4 * 4 + j;
        float v = acc[i][jn][j] + bval;
        if (EPI == 0) {
          Cf[(size_t)m * 1024 + n] = v;
        } else {
          int which = n >> 10, hh = (n >> 6) & 15, d = n & 63;
          int bb = m >> 11, pos = m & 2047;
          int bhh = bb * 16 + hh;
          if (which == 0)
            qb[((size_t)bhh * 2048 + pos) * 64 + d] = f2bf(v * 0.18033688f);  // 0.125*log2(e)
          else if (which == 1)
            kb[((size_t)bhh * 2048 + pos) * 64 + d] = f2bf(v);
          else
            vtb[((size_t)bhh * 64 + d) * 2048 + pos] = f2bf(v);
        }
      }
    }
  }
}

// ---------------- flash attention, swapped-QK^T in-register softmax ----------------
// grid (8, 32); 512 thr = 8 waves; wave owns 32 q rows (2 q-frags); KVBLK=64, dbuf.
__global__ __launch_bounds__(512) void k_attn(const unsigned short* __restrict__ qbuf,
                                              const unsigned short* __restrict__ kbuf,
                                              const unsigned short* __restrict__ vtbuf,
                                              const float* __restrict__ biash,
                                              unsigned short* __restrict__ aout) {
  __shared__ unsigned short Klds[2][64 * 64];
  __shared__ unsigned short Vlds[2][64 * 64];
  __shared__ unsigned short Plds[8][32 * 80];       // per-wave P, stride 80 shorts
  __shared__ unsigned short blds[4 * 2304];         // bias window, 4 shift-replicas, bf16

  const int t = threadIdx.x;
  const int w = t >> 6, l = t & 63;
  const int l15 = l & 15, l4 = l >> 4;
  const int bh = blockIdx.y;
  const int h = bh & 15, b = bh >> 4;
  const int qbase = blockIdx.x * 256;

  // Q fragments: 2 q-frags x 2 d-halves
  bf16x8 qA[2][2];
#pragma unroll
  for (int qf = 0; qf < 2; ++qf) {
    const size_t qoff = ((size_t)bh * 2048 + qbase + w * 32 + qf * 16 + l15) * 64;
    qA[qf][0] = *(const bf16x8*)&qbuf[qoff + l4 * 8];
    qA[qf][1] = *(const bf16x8*)&qbuf[qoff + 32 + l4 * 8];
  }

  f32x4 O[2][4];
#pragma unroll
  for (int qf = 0; qf < 2; ++qf)
#pragma unroll
    for (int df = 0; df < 4; ++df) O[qf][df] = (f32x4){0.f, 0.f, 0.f, 0.f};
  float m_run[2] = {-3e38f, -3e38f}, l_run[2] = {0.f, 0.f};

  const int srow = t >> 3;                 // 0..63
  const int scl = (t & 7) ^ (srow & 7);
  const unsigned short* kg = kbuf + ((size_t)bh * 2048 + srow) * 64 + scl * 8;
  const unsigned short* vg = vtbuf + ((size_t)bh * 64 + srow) * 2048 + scl * 8;

  // prologue: bias window (bf16, 4 replicas shifted by c) + K/V tile 0
  gld_lds16(kg, &Klds[0][t * 8]);
  gld_lds16(vg, &Vlds[0][t * 8]);
  {
    const float* win = biash + h * 4096 + (1792 - qbase);
#pragma unroll
    for (int c = 0; c < 4; ++c)
      for (int j = t; j < 2304; j += 512) {
        int src = j + c;
        blds[c * 2304 + j] = (src <= 2302) ? f2bf(win[src]) : (unsigned short)0;
      }
  }
  __syncthreads();

  // hoisted bias base offsets per (qf,f): i = kbase + delta + r, delta lane-const
  int woff[2][4];
#pragma unroll
  for (int qf = 0; qf < 2; ++qf)
#pragma unroll
    for (int f = 0; f < 4; ++f) {
      int delta = f * 16 - qf * 16 + 4 * l4 - w * 32 - l15 + 255;
      int c = delta & 3;
      woff[qf][f] = c * 2304 + delta - c;
    }

  unsigned short* pw = &Plds[w][0];
  const int sw = l15 & 7;

  for (int kt = 0; kt < 32; ++kt) {
    const int cur = kt & 1;
    if (kt < 31) {
      gld_lds16(kg + (size_t)(kt + 1) * 64 * 64, &Klds[cur ^ 1][t * 8]);
      gld_lds16(vg + (kt + 1) * 64, &Vlds[cur ^ 1][t * 8]);
    }
    const int kbase = kt * 64;

    // QK^T swapped: s[qf][f][r] = S[k = 16f+4*l4+r][q = qf*16+l15]
    float s[2][4][4];
    __builtin_amdgcn_s_setprio(1);
#pragma unroll
    for (int f = 0; f < 4; ++f) {
      int kr = f * 16 + l15;
      bf16x8 k0 = *(const bf16x8*)&Klds[cur][kr * 64 + ((l4 ^ sw)) * 8];
      bf16x8 k1 = *(const bf16x8*)&Klds[cur][kr * 64 + (((4 + l4) ^ sw)) * 8];
#pragma unroll
      for (int qf = 0; qf < 2; ++qf) {
        f32x4 facc = (f32x4){0.f, 0.f, 0.f, 0.f};
        facc = __builtin_amdgcn_mfma_f32_16x16x32_bf16(k0, qA[qf][0], facc, 0, 0, 0);
        facc = __builtin_amdgcn_mfma_f32_16x16x32_bf16(k1, qA[qf][1], facc, 0, 0, 0);
#pragma unroll
        for (int r = 0; r < 4; ++r) s[qf][f][r] = facc[r];
      }
    }
    __builtin_amdgcn_s_setprio(0);

    // bias add: one ds_read_b64 (4 bf16) per (qf,f)
#pragma unroll
    for (int qf = 0; qf < 2; ++qf)
#pragma unroll
      for (int f = 0; f < 4; ++f) {
        u32x2 bw = *(const u32x2*)&blds[woff[qf][f] + kbase];
        s[qf][f][0] += __uint_as_float(bw.x << 16);
        s[qf][f][1] += __uint_as_float(bw.x & 0xffff0000u);
        s[qf][f][2] += __uint_as_float(bw.y << 16);
        s[qf][f][3] += __uint_as_float(bw.y & 0xffff0000u);
      }

    // in-register max over 16 + 2 shfl (reduce across l4 groups)
    float mx[2], alpha[2] = {1.f, 1.f};
#pragma unroll
    for (int qf = 0; qf < 2; ++qf) {
      float a0 = fmaxf(fmaxf(s[qf][0][0], s[qf][0][1]), fmaxf(s[qf][0][2], s[qf][0][3]));
      float a1 = fmaxf(fmaxf(s[qf][1][0], s[qf][1][1]), fmaxf(s[qf][1][2], s[qf][1][3]));
      float a2 = fmaxf(fmaxf(s[qf][2][0], s[qf][2][1]), fmaxf(s[qf][2][2], s[qf][2][3]));
      float a3 = fmaxf(fmaxf(s[qf][3][0], s[qf][3][1]), fmaxf(s[qf][3][2], s[qf][3][3]));
      float m16 = fmaxf(fmaxf(a0, a1), fmaxf(a2, a3));
      m16 = fmaxf(m16, __shfl_xor(m16, 16));
      m16 = fmaxf(m16, __shfl_xor(m16, 32));
      mx[qf] = m16;
    }

    // defer-max: rescale only when running max grows by > 8 (log2 units)
    if (__any((mx[0] > m_run[0] + 8.f) || (mx[1] > m_run[1] + 8.f))) {
#pragma unroll
      for (int qf = 0; qf < 2; ++qf) {
        float mnew = fmaxf(m_run[qf], mx[qf]);
        alpha[qf] = exp2_fast(m_run[qf] - mnew);
        m_run[qf] = mnew;
      }
#pragma unroll
      for (int qf = 0; qf < 2; ++qf)
#pragma unroll
        for (int j = 0; j < 4; ++j) {
          float aj = __shfl(alpha[qf], (l & 48) | (l4 * 4 + j));
#pragma unroll
          for (int df = 0; df < 4; ++df) O[qf][df][j] *= aj;
        }
    }

    // exp + row-sum
#pragma unroll
    for (int qf = 0; qf < 2; ++qf) {
#pragma unroll
      for (int f = 0; f < 4; ++f)
#pragma unroll
        for (int r = 0; r < 4; ++r) s[qf][f][r] = exp2_fast(s[qf][f][r] - m_run[qf]);
      float r0 = (s[qf][0][0] + s[qf][0][1]) + (s[qf][0][2] + s[qf][0][3]);
      float r1 = (s[qf][1][0] + s[qf][1][1]) + (s[qf][1][2] + s[qf][1][3]);
      float r2 = (s[qf][2][0] + s[qf][2][1]) + (s[qf][2][2] + s[qf][2][3]);
      float r3 = (s[qf][3][0] + s[qf][3][1]) + (s[qf][3][2] + s[qf][3][3]);
      float rs = (r0 + r1) + (r2 + r3);
      rs += __shfl_xor(rs, 16);
      rs += __shfl_xor(rs, 32);
      l_run[qf] = l_run[qf] * alpha[qf] + rs;
    }

    // P pack (cvt_pk) -> LDS  [rows q, stride 80 shorts]
#pragma unroll
    for (int qf = 0; qf < 2; ++qf)
#pragma unroll
      for (int f = 0; f < 4; ++f) {
        u32x2 pk;
        pk.x = cvt_pk_bf16(s[qf][f][0], s[qf][f][1]);
        pk.y = cvt_pk_bf16(s[qf][f][2], s[qf][f][3]);
        *(u32x2*)&pw[(qf * 16 + l15) * 80 + f * 16 + l4 * 4] = pk;
      }

    // V fragments (shared across qf) + PV
    bf16x8 v0[4], v1[4];
#pragma unroll
    for (int df = 0; df < 4; ++df) {
      int vr = df * 16 + l15;
      v0[df] = *(const bf16x8*)&Vlds[cur][vr * 64 + ((l4 ^ sw)) * 8];
      v1[df] = *(const bf16x8*)&Vlds[cur][vr * 64 + (((4 + l4) ^ sw)) * 8];
    }
    __builtin_amdgcn_s_setprio(1);
#pragma unroll
    for (int qf = 0; qf < 2; ++qf) {
      bf16x8 pa0 = *(const bf16x8*)&pw[(qf * 16 + l15) * 80 + l4 * 8];
      bf16x8 pa1 = *(const bf16x8*)&pw[(qf * 16 + l15) * 80 + 32 + l4 * 8];
#pragma unroll
      for (int df = 0; df < 4; ++df) {
        O[qf][df] = __builtin_amdgcn_mfma_f32_16x16x32_bf16(pa0, v0[df], O[qf][df], 0, 0, 0);
        O[qf][df] = __builtin_amdgcn_mfma_f32_16x16x32_bf16(pa1, v1[df], O[qf][df], 0, 0, 0);
      }
    }
    __builtin_amdgcn_s_setprio(0);

    __syncthreads();  // drains prefetch vmcnt; publishes next buffer
  }

  // epilogue: normalize + store
#pragma unroll
  for (int qf = 0; qf < 2; ++qf) {
    float linv[4];
#pragma unroll
    for (int j = 0; j < 4; ++j)
      linv[j] = 1.f / __shfl(l_run[qf], (l & 48) | (l4 * 4 + j));
#pragma unroll
    for (int df = 0; df < 4; ++df)
#pragma unroll
      for (int j = 0; j < 4; ++j) {
        float v = O[qf][df][j] * linv[j];
        int q = qbase + w * 32 + qf * 16 + l4 * 4 + j;
        int col = h * 64 + df * 16 + l15;
        aout[((size_t)b * 2048 + q) * 1024 + col] = f2bf(v);
      }
  }
}

// ---------------- launch ----------------

extern "C" void kernel_launch(void* const* d_in, const int* in_sizes, int n_in,
                              void* d_out, int out_size, void* d_ws, size_t ws_size,
                              hipStream_t stream) {
  const float* x = (const float*)d_in[0];
  const float* qkv_w = (const float*)d_in[1];
  const float* qkv_b = (const float*)d_in[2];
  const float* proj_w = (const float*)d_in[3];
  const float* proj_b = (const float*)d_in[4];
  const float* bias_table = (const float*)d_in[5];
  float* out = (float*)d_out;

  char* ws = (char*)d_ws;
  unsigned short* xb = (unsigned short*)(ws);                          // 8 MB, reused as attn_out
  unsigned short* wqkv = (unsigned short*)(ws + (size_t)(8u << 20));   // 6 MB
  unsigned short* wproj = (unsigned short*)(ws + (size_t)(14u << 20)); // 2 MB
  unsigned short* qb = (unsigned short*)(ws + (size_t)(16u << 20));    // 8 MB
  unsigned short* kb = (unsigned short*)(ws + (size_t)(24u << 20));    // 8 MB
  unsigned short* vtb = (unsigned short*)(ws + (size_t)(32u << 20));   // 8 MB
  float* biash = (float*)(ws + (size_t)(40u << 20));                   // 256 KB

  unsigned short* attn_out = xb;  // xb is dead after the qkv GEMM

  k_convert_x<<<dim3(4096), dim3(256), 0, stream>>>((const float4*)x, (ushort4*)xb);
  k_transpose_bf16<<<dim3(96, 32), dim3(32, 8), 0, stream>>>(qkv_w, wqkv, 1024, 3072);
  k_transpose_bf16<<<dim3(32, 32), dim3(32, 8), 0, stream>>>(proj_w, wproj, 1024, 1024);
  k_bias_cols<<<dim3(256), dim3(256), 0, stream>>>(bias_table, biash);

  k_gemm<1><<<dim3(24, 32), dim3(256), 0, stream>>>(xb, wqkv, qkv_b, nullptr, qb, kb, vtb);
  k_attn<<<dim3(8, 32), dim3(512), 0, stream>>>(qb, kb, vtb, biash, attn_out);
  k_gemm<0><<<dim3(8, 32), dim3(256), 0, stream>>>(attn_out, wproj, proj_b, out, nullptr, nullptr,
                                                   nullptr);
}

// Round 5
// 168.845 us; speedup vs baseline: 1.2385x; 1.0187x over previous
//
#include <hip/hip_runtime.h>

typedef short bf16x4 __attribute__((ext_vector_type(4)));
typedef short bf16x8 __attribute__((ext_vector_type(8)));
typedef float f32x4 __attribute__((ext_vector_type(4)));
typedef float f32x16 __attribute__((ext_vector_type(16)));

__device__ __forceinline__ unsigned short f2bf(float f) {
  union { float f; unsigned int u; } v; v.f = f;
  unsigned int r = v.u + 0x7FFFu + ((v.u >> 16) & 1u);
  return (unsigned short)(r >> 16);
}

__device__ __forceinline__ float exp2_fast(float x) {
  float r;
  asm("v_exp_f32 %0, %1" : "=v"(r) : "v"(x));
  return r;
}

__device__ __forceinline__ unsigned int cvt_pk_bf16(float lo, float hi) {
  unsigned int r;
  asm("v_cvt_pk_bf16_f32 %0, %1, %2" : "=v"(r) : "v"(lo), "v"(hi));
  return r;
}

__device__ __forceinline__ void gld_lds16(const void* g, void* l) {
  __builtin_amdgcn_global_load_lds(
      (const __attribute__((address_space(1))) unsigned int*)g,
      (__attribute__((address_space(3))) unsigned int*)l, 16, 0, 0);
}

// ---------------- prep kernels ----------------

__global__ __launch_bounds__(256) void k_convert_x(const float4* __restrict__ in,
                                                   ushort4* __restrict__ out) {
  int id = blockIdx.x * 256 + threadIdx.x;
  float4 v = in[id];
  ushort4 o;
  o.x = f2bf(v.x); o.y = f2bf(v.y); o.z = f2bf(v.z); o.w = f2bf(v.w);
  out[id] = o;
}

// in [R][C] fp32 -> out [C][R] bf16
__global__ __launch_bounds__(256) void k_transpose_bf16(const float* __restrict__ in,
                                                        unsigned short* __restrict__ out,
                                                        int R, int C) {
  __shared__ float tile[32][33];
  int tx = threadIdx.x, ty = threadIdx.y;
  int c0 = blockIdx.x * 32, r0 = blockIdx.y * 32;
#pragma unroll
  for (int i = 0; i < 32; i += 8) tile[ty + i][tx] = in[(size_t)(r0 + ty + i) * C + c0 + tx];
  __syncthreads();
#pragma unroll
  for (int i = 0; i < 32; i += 8) out[(size_t)(c0 + ty + i) * R + r0 + tx] = f2bf(tile[tx][ty + i]);
}

// bias_table [4095][16] -> biash [16][4096], scaled by log2(e)
__global__ __launch_bounds__(256) void k_bias_cols(const float* __restrict__ bt,
                                                   float* __restrict__ bh) {
  int i = blockIdx.x * 256 + threadIdx.x;
  if (i < 4095 * 16) bh[(i & 15) * 4096 + (i >> 4)] = bt[i] * 1.44269504089f;
}

// ---------------- GEMM: C[M][N] = A[M][1024] * Bt[N][1024]^T (+bias) ----------------
template <int EPI>
__global__ __launch_bounds__(256) void k_gemm(const unsigned short* __restrict__ A,
                                              const unsigned short* __restrict__ Bt,
                                              const float* __restrict__ bias,
                                              float* __restrict__ Cf,
                                              unsigned short* __restrict__ qb,
                                              unsigned short* __restrict__ kb,
                                              unsigned short* __restrict__ vtb) {
  __shared__ unsigned short Alds[128 * 64];
  __shared__ unsigned short Blds[128 * 64];
  const int t = threadIdx.x;
  const int l = t & 63, w = t >> 6;
  const int l15 = l & 15, l4 = l >> 4;
  const int wm = w >> 1, wn = w & 1;
  const int bm = blockIdx.y * 128, bn = blockIdx.x * 128;

  const int srow = t >> 3;
  const int scl = (t & 7) ^ (srow & 7);
  const unsigned short* ag = A + (size_t)(bm + srow) * 1024 + scl * 8;
  const unsigned short* bg = Bt + (size_t)(bn + srow) * 1024 + scl * 8;

  f32x4 acc[4][4];
#pragma unroll
  for (int i = 0; i < 4; ++i)
#pragma unroll
    for (int j = 0; j < 4; ++j) acc[i][j] = (f32x4){0.f, 0.f, 0.f, 0.f};

  for (int kt = 0; kt < 16; ++kt) {
#pragma unroll
    for (int q = 0; q < 4; ++q) {
      gld_lds16(ag + (size_t)q * 32 * 1024 + kt * 64, &Alds[(q * 256 + t) * 8]);
      gld_lds16(bg + (size_t)q * 32 * 1024 + kt * 64, &Blds[(q * 256 + t) * 8]);
    }
    __syncthreads();
#pragma unroll
    for (int kc = 0; kc < 2; ++kc) {
      bf16x8 af[4], bv[4];
#pragma unroll
      for (int i = 0; i < 4; ++i) {
        int ra = wm * 64 + i * 16 + l15;
        af[i] = *(const bf16x8*)&Alds[ra * 64 + (((kc * 4 + l4) ^ (l15 & 7))) * 8];
        int rb = wn * 64 + i * 16 + l15;
        bv[i] = *(const bf16x8*)&Blds[rb * 64 + (((kc * 4 + l4) ^ (l15 & 7))) * 8];
      }
#pragma unroll
      for (int i = 0; i < 4; ++i)
#pragma unroll
        for (int jn = 0; jn < 4; ++jn)
          acc[i][jn] = __builtin_amdgcn_mfma_f32_16x16x32_bf16(af[i], bv[jn], acc[i][jn], 0, 0, 0);
    }
    __syncthreads();
  }

#pragma unroll
  for (int i = 0; i < 4; ++i) {
#pragma unroll
    for (int jn = 0; jn < 4; ++jn) {
      int n = bn + wn * 64 + jn * 16 + l15;
      float bval = bias[n];
#pragma unroll
      for (int j = 0; j < 4; ++j) {
        int m = bm + wm * 64 + i * 16 + l4 * 4 + j;
        float v = acc[i][jn][j] + bval;
        if (EPI == 0) {
          Cf[(size_t)m * 1024 + n] = v;
        } else {
          int which = n >> 10, hh = (n >> 6) & 15, d = n & 63;
          int bb = m >> 11, pos = m & 2047;
          int bhh = bb * 16 + hh;
          if (which == 0)
            qb[((size_t)bhh * 2048 + pos) * 64 + d] = f2bf(v * 0.18033688f);  // 0.125*log2(e)
          else if (which == 1)
            kb[((size_t)bhh * 2048 + pos) * 64 + d] = f2bf(v);
          else
            vtb[((size_t)bhh * 64 + d) * 2048 + pos] = f2bf(v);
        }
      }
    }
  }
}

// ---------------- flash attention, 32x32 MFMA, swapped QK^T, P fully in-register ----
// grid (16, 32); 256 thr = 4 waves; wave owns 32 q rows; KVBLK=64.
// Staging: reg-staged (T14) — issue global loads early, ds_write (swizzled) late,
// single __syncthreads per tile. No global_load_lds in this kernel.
__global__ __launch_bounds__(256) void k_attn(const unsigned short* __restrict__ qbuf,
                                              const unsigned short* __restrict__ kbuf,
                                              const unsigned short* __restrict__ vtbuf,
                                              const float* __restrict__ biash,
                                              unsigned short* __restrict__ aout) {
  __shared__ __align__(16) unsigned short Klds[2][64 * 64];
  __shared__ __align__(16) unsigned short Vlds[2][64 * 64];
  __shared__ __align__(16) float blds[4 * 2308];  // 4 shift-replicas, stride 2308

  const int t = threadIdx.x;
  const int w = t >> 6, l = t & 63;
  const int l31 = l & 31, hi = l >> 5;
  const int bh = blockIdx.y;
  const int h = bh & 15, b = bh >> 4;
  const int qbase = blockIdx.x * 128;
  const int wq = qbase + w * 32;

  // Q B-operand regs: lane l31 = q-col, slot (hi,e) = d = 16*ds + 8*hi + e
  bf16x8 qB[4];
  {
    const unsigned short* qrow = qbuf + ((size_t)bh * 2048 + wq + l31) * 64;
#pragma unroll
    for (int ds = 0; ds < 4; ++ds) qB[ds] = *(const bf16x8*)&qrow[ds * 16 + hi * 8];
  }

  f32x16 O[2];
#pragma unroll
  for (int i = 0; i < 16; ++i) { O[0][i] = 0.f; O[1][i] = 0.f; }
  float m_run = -3e38f, l_run = 0.f;

  // staging: linear global source; swizzled LDS write offset
  const int c0r = t >> 3, c0c = t & 7;  // rows 0..31 (+32 for second half), 8 chunks/row
  const unsigned short* kg = kbuf + ((size_t)bh * 2048 + c0r) * 64 + c0c * 8;
  const unsigned short* vg = vtbuf + ((size_t)bh * 64 + c0r) * 2048 + c0c * 8;
  const int wKV = c0r * 64 + ((c0c ^ (c0r & 7)) * 8);  // shorts; row+32 keeps same XOR

  // prologue: stage tile 0 + bias replicas (all plain loads/stores; blds fully init)
  {
    bf16x8 k0 = *(const bf16x8*)(kg);
    bf16x8 k1 = *(const bf16x8*)(kg + 32 * 64);
    bf16x8 v0 = *(const bf16x8*)(vg);
    bf16x8 v1 = *(const bf16x8*)(vg + 32 * 2048);
    *(bf16x8*)&Klds[0][wKV] = k0;
    *(bf16x8*)&Klds[0][wKV + 2048] = k1;
    *(bf16x8*)&Vlds[0][wKV] = v0;
    *(bf16x8*)&Vlds[0][wKV + 2048] = v1;
    const float* win = biash + h * 4096 + (1920 - qbase);
    for (int j = t; j < 2308; j += 256) {
#pragma unroll
      for (int c = 0; c < 4; ++c) {
        float v = (j + c <= 2174) ? win[j + c] : 0.f;
        blds[c * 2308 + j] = v;
      }
    }
  }
  __syncthreads();

  // per-lane bias base: quad(kt2,g): word = bbase + kbase + 32*kt2 + 8*g (16B aligned)
  const int cb = (127 - l31) & 3;
  const float* bbase = blds + (cb * 2308 + 127 - l31 - 32 * w + 4 * hi - cb);

  for (int kt = 0; kt < 32; ++kt) {
    const int cur = kt & 1;

    // T14 issue-early: next tile global loads into regs
    bf16x8 kst0, kst1, vst0, vst1;
    if (kt < 31) {
      const unsigned short* kga = kg + (size_t)(kt + 1) * 4096;
      const unsigned short* vga = vg + (kt + 1) * 64;
      kst0 = *(const bf16x8*)(kga);
      kst1 = *(const bf16x8*)(kga + 32 * 64);
      vst0 = *(const bf16x8*)(vga);
      vst1 = *(const bf16x8*)(vga + 32 * 2048);
    }
    const int kbase = kt * 64;

    // QK^T swapped: sacc C-layout: col=l31=q, row(reg)=(reg&3)+8*(reg>>2)+4*hi = k-local
    f32x16 sacc[2];
#pragma unroll
    for (int i = 0; i < 16; ++i) { sacc[0][i] = 0.f; sacc[1][i] = 0.f; }
    __builtin_amdgcn_s_setprio(1);
#pragma unroll
    for (int kt2 = 0; kt2 < 2; ++kt2) {
      int row = kt2 * 32 + l31;
      int rsw = row & 7;
#pragma unroll
      for (int ds = 0; ds < 4; ++ds) {
        bf16x8 ka = *(const bf16x8*)&Klds[cur][row * 64 + (((2 * ds + hi) ^ rsw) * 8)];
        sacc[kt2] = __builtin_amdgcn_mfma_f32_32x32x16_bf16(ka, qB[ds], sacc[kt2], 0, 0, 0);
      }
    }
    __builtin_amdgcn_s_setprio(0);

    // bias add: 8 x ds_read_b128 (f32x4)
#pragma unroll
    for (int kt2 = 0; kt2 < 2; ++kt2)
#pragma unroll
      for (int g = 0; g < 4; ++g) {
        f32x4 bq = *(const f32x4*)&bbase[kbase + 32 * kt2 + 8 * g];
#pragma unroll
        for (int r = 0; r < 4; ++r) sacc[kt2][4 * g + r] += bq[r];
      }

    // max over own 32 + 1 cross-half swap
    float mx;
    {
      float q0 = fmaxf(fmaxf(sacc[0][0], sacc[0][1]), fmaxf(sacc[0][2], sacc[0][3]));
      float q1 = fmaxf(fmaxf(sacc[0][4], sacc[0][5]), fmaxf(sacc[0][6], sacc[0][7]));
      float q2 = fmaxf(fmaxf(sacc[0][8], sacc[0][9]), fmaxf(sacc[0][10], sacc[0][11]));
      float q3 = fmaxf(fmaxf(sacc[0][12], sacc[0][13]), fmaxf(sacc[0][14], sacc[0][15]));
      float q4 = fmaxf(fmaxf(sacc[1][0], sacc[1][1]), fmaxf(sacc[1][2], sacc[1][3]));
      float q5 = fmaxf(fmaxf(sacc[1][4], sacc[1][5]), fmaxf(sacc[1][6], sacc[1][7]));
      float q6 = fmaxf(fmaxf(sacc[1][8], sacc[1][9]), fmaxf(sacc[1][10], sacc[1][11]));
      float q7 = fmaxf(fmaxf(sacc[1][12], sacc[1][13]), fmaxf(sacc[1][14], sacc[1][15]));
      mx = fmaxf(fmaxf(fmaxf(q0, q1), fmaxf(q2, q3)), fmaxf(fmaxf(q4, q5), fmaxf(q6, q7)));
      mx = fmaxf(mx, __shfl_xor(mx, 32));
    }

    // defer-max rescale (THR=8, log2 domain)
    if (__any(mx > m_run + 8.f)) {
      float mnew = fmaxf(m_run, mx);
      float alpha = exp2_fast(m_run - mnew);
      m_run = mnew;
      l_run *= alpha;
#pragma unroll
      for (int g = 0; g < 4; ++g)
#pragma unroll
        for (int r = 0; r < 4; ++r) {
          float a_lo = __shfl(alpha, 8 * g + r);
          float a_hi = __shfl(alpha, 8 * g + r + 4);
          float aq = hi ? a_hi : a_lo;
          O[0][4 * g + r] *= aq;
          O[1][4 * g + r] *= aq;
        }
    }

    // exp + row-sum (own 32 + 1 swap)
#pragma unroll
    for (int kt2 = 0; kt2 < 2; ++kt2)
#pragma unroll
      for (int i = 0; i < 16; ++i) sacc[kt2][i] = exp2_fast(sacc[kt2][i] - m_run);
    {
      float s0 = (sacc[0][0] + sacc[0][1]) + (sacc[0][2] + sacc[0][3]);
      float s1 = (sacc[0][4] + sacc[0][5]) + (sacc[0][6] + sacc[0][7]);
      float s2 = (sacc[0][8] + sacc[0][9]) + (sacc[0][10] + sacc[0][11]);
      float s3 = (sacc[0][12] + sacc[0][13]) + (sacc[0][14] + sacc[0][15]);
      float s4 = (sacc[1][0] + sacc[1][1]) + (sacc[1][2] + sacc[1][3]);
      float s5 = (sacc[1][4] + sacc[1][5]) + (sacc[1][6] + sacc[1][7]);
      float s6 = (sacc[1][8] + sacc[1][9]) + (sacc[1][10] + sacc[1][11]);
      float s7 = (sacc[1][12] + sacc[1][13]) + (sacc[1][14] + sacc[1][15]);
      float rs = ((s0 + s1) + (s2 + s3)) + ((s4 + s5) + (s6 + s7));
      rs += __shfl_xor(rs, 32);
      l_run += rs;
    }

    // P pack: PV A-operand = own regs pairwise cvt_pk (sigma-permuted contract slots)
    bf16x8 pa[2][2];
#pragma unroll
    for (int kt2 = 0; kt2 < 2; ++kt2)
#pragma unroll
      for (int mm = 0; mm < 2; ++mm) {
        union { unsigned int u[4]; bf16x8 v; } pk;
        pk.u[0] = cvt_pk_bf16(sacc[kt2][8 * mm + 0], sacc[kt2][8 * mm + 1]);
        pk.u[1] = cvt_pk_bf16(sacc[kt2][8 * mm + 2], sacc[kt2][8 * mm + 3]);
        pk.u[2] = cvt_pk_bf16(sacc[kt2][8 * mm + 4], sacc[kt2][8 * mm + 5]);
        pk.u[3] = cvt_pk_bf16(sacc[kt2][8 * mm + 6], sacc[kt2][8 * mm + 7]);
        pa[kt2][mm] = pk.v;
      }

    // PV: O[dt] += P * V ; V slot (hi,e): k = 32*kt2 + 16*mm + 8*(e>>2) + 4*hi + (e&3)
    __builtin_amdgcn_s_setprio(1);
#pragma unroll
    for (int dt = 0; dt < 2; ++dt) {
      int row = dt * 32 + l31;
      int rsw = row & 7;
#pragma unroll
      for (int kt2 = 0; kt2 < 2; ++kt2)
#pragma unroll
        for (int mm = 0; mm < 2; ++mm) {
          int cA = (4 * kt2 + 2 * mm) ^ rsw;
          int cB = (4 * kt2 + 2 * mm + 1) ^ rsw;
          bf16x4 vlo = *(const bf16x4*)&Vlds[cur][row * 64 + cA * 8 + 4 * hi];
          bf16x4 vhi = *(const bf16x4*)&Vlds[cur][row * 64 + cB * 8 + 4 * hi];
          bf16x8 vb = __builtin_shufflevector(vlo, vhi, 0, 1, 2, 3, 4, 5, 6, 7);
          O[dt] = __builtin_amdgcn_mfma_f32_32x32x16_bf16(pa[kt2][mm], vb, O[dt], 0, 0, 0);
        }
    }
    __builtin_amdgcn_s_setprio(0);

    // T14 write-late: publish next tile (waits vmcnt internally via reg deps)
    if (kt < 31) {
      *(bf16x8*)&Klds[cur ^ 1][wKV] = kst0;
      *(bf16x8*)&Klds[cur ^ 1][wKV + 2048] = kst1;
      *(bf16x8*)&Vlds[cur ^ 1][wKV] = vst0;
      *(bf16x8*)&Vlds[cur ^ 1][wKV + 2048] = vst1;
    }
    __syncthreads();
  }

  // epilogue: gather 1/l per O-row, scale, store (O lane = d-col)
  {
    float linv = 1.f / l_run;
#pragma unroll
    for (int g = 0; g < 4; ++g)
#pragma unroll
      for (int r = 0; r < 4; ++r) {
        float v_lo = __shfl(linv, 8 * g + r);
        float v_hi = __shfl(linv, 8 * g + r + 4);
        float sc = hi ? v_hi : v_lo;
        int q = wq + 8 * g + r + 4 * hi;
        size_t base = ((size_t)b * 2048 + q) * 1024 + h * 64 + l31;
        aout[base] = f2bf(O[0][4 * g + r] * sc);
        aout[base + 32] = f2bf(O[1][4 * g + r] * sc);
      }
  }
}

// ---------------- launch ----------------

extern "C" void kernel_launch(void* const* d_in, const int* in_sizes, int n_in,
                              void* d_out, int out_size, void* d_ws, size_t ws_size,
                              hipStream_t stream) {
  const float* x = (const float*)d_in[0];
  const float* qkv_w = (const float*)d_in[1];
  const float* qkv_b = (const float*)d_in[2];
  const float* proj_w = (const float*)d_in[3];
  const float* proj_b = (const float*)d_in[4];
  const float* bias_table = (const float*)d_in[5];
  float* out = (float*)d_out;

  char* ws = (char*)d_ws;
  unsigned short* xb = (unsigned short*)(ws);                          // 8 MB, reused as attn_out
  unsigned short* wqkv = (unsigned short*)(ws + (size_t)(8u << 20));   // 6 MB
  unsigned short* wproj = (unsigned short*)(ws + (size_t)(14u << 20)); // 2 MB
  unsigned short* qb = (unsigned short*)(ws + (size_t)(16u << 20));    // 8 MB
  unsigned short* kb = (unsigned short*)(ws + (size_t)(24u << 20));    // 8 MB
  unsigned short* vtb = (unsigned short*)(ws + (size_t)(32u << 20));   // 8 MB
  float* biash = (float*)(ws + (size_t)(40u << 20));                   // 256 KB

  unsigned short* attn_out = xb;  // xb is dead after the qkv GEMM

  k_convert_x<<<dim3(4096), dim3(256), 0, stream>>>((const float4*)x, (ushort4*)xb);
  k_transpose_bf16<<<dim3(96, 32), dim3(32, 8), 0, stream>>>(qkv_w, wqkv, 1024, 3072);
  k_transpose_bf16<<<dim3(32, 32), dim3(32, 8), 0, stream>>>(proj_w, wproj, 1024, 1024);
  k_bias_cols<<<dim3(256), dim3(256), 0, stream>>>(bias_table, biash);

  k_gemm<1><<<dim3(24, 32), dim3(256), 0, stream>>>(xb, wqkv, qkv_b, nullptr, qb, kb, vtb);
  k_attn<<<dim3(16, 32), dim3(256), 0, stream>>>(qb, kb, vtb, biash, attn_out);
  k_gemm<0><<<dim3(8, 32), dim3(256), 0, stream>>>(attn_out, wproj, proj_b, out, nullptr, nullptr,
                                                   nullptr);
}